// Round 3
// baseline (58.836 us; speedup 1.0000x reference)
//
#include <hip/hip_runtime.h>
#include <math.h>

// LightingProbes R3: selection on separable d2 (no sqrt in key), ascending
// probe-index iteration + strict < (exact R1/R2 tie semantics). 2 points per
// thread (striped) for in-wave ILP. uv/face/gather path bit-identical to R2.

#define NTEX 192000   // 125*6*16*16 texels

__device__ __forceinline__ float fastrcp(float x)  { return __builtin_amdgcn_rcpf(x); }
__device__ __forceinline__ float fastsqrt(float x) { return __builtin_amdgcn_sqrtf(x); }

__device__ __forceinline__ int dim_start(float v) {
    float f = (v + 3.0f) * (1.0f / 1.5f);
    int n = (int)floorf(f + 0.5f);
    n = n < 0 ? 0 : (n > 4 ? 4 : n);
    int s = n - 1;
    s = s < 0 ? 0 : (s > 2 ? 2 : s);
    return s;
}

// per-dim squared errors for the 3 candidate coords starting at s
__device__ __forceinline__ int dimprep(float v, float e[3]) {
    int s = dim_start(v);
    float p0 = fmaf(1.5f, (float)s, -3.0f);
    float d0 = v - p0;
    float d1 = d0 - 1.5f;
    float d2 = d1 - 1.5f;
    e[0] = d0 * d0; e[1] = d1 * d1; e[2] = d2 * d2;
    return s;
}

// sorted top-4 insert (ascending), strict < keeps earlier (lower idx) on tie
#define INSERT(d, L, s0, s1, s2, s3, k0, k1, k2, k3)                          \
    {                                                                         \
        bool lt = (d) < s3; s3 = lt ? (d) : s3; k3 = lt ? (L) : k3;           \
        { bool cb = s3 < s2; float nd = cb ? s3 : s2, xd = cb ? s2 : s3;      \
          int ni = cb ? k3 : k2, xi = cb ? k2 : k3;                           \
          s2 = nd; s3 = xd; k2 = ni; k3 = xi; }                               \
        { bool cb = s2 < s1; float nd = cb ? s2 : s1, xd = cb ? s1 : s2;      \
          int ni = cb ? k2 : k1, xi = cb ? k1 : k2;                           \
          s1 = nd; s2 = xd; k1 = ni; k2 = xi; }                               \
        { bool cb = s1 < s0; float nd = cb ? s1 : s0, xd = cb ? s0 : s1;      \
          int ni = cb ? k1 : k0, xi = cb ? k0 : k1;                           \
          s0 = nd; s1 = xd; k0 = ni; k1 = xi; }                               \
    }

// ---- uv/face/bilinear — BIT-IDENTICAL math to R2 ----
__device__ __forceinline__ void uv_setup(
    float dx, float dy, float dz,
    int& face, int& t00, int& t01, int& t10, int& t11,
    float& w00, float& w01, float& w10, float& w11)
{
    float nrm = sqrtf(fmaf(dx, dx, fmaf(dy, dy, dz * dz)));
    nrm = fmaxf(nrm, 1e-12f);
    float inv = fastrcp(nrm);
    float ux = dx * inv, uy = dy * inv, uz = dz * inv;
    float ax = fabsf(ux), ay = fabsf(uy), az = fabsf(uz);

    bool xd = (ax >= ay) && (ax >= az);
    float den, un, vn;
    if (xd) {
        face = (ux > 0.0f) ? 0 : 1;
        den = ax; un = (ux > 0.0f) ? -uz : uz; vn = -uy;
    } else if (ay >= az) {
        face = (uy > 0.0f) ? 2 : 3;
        den = ay; un = ux; vn = (uy > 0.0f) ? uz : -uz;
    } else {
        face = (uz > 0.0f) ? 4 : 5;
        den = az; un = (uz > 0.0f) ? ux : -ux; vn = -uy;
    }
    float rden = fastrcp(den + 1e-8f);
    float u = un * rden;
    float v = vn * rden;
    u = fminf(1.0f, fmaxf(-1.0f, u));
    v = fminf(1.0f, fmaxf(-1.0f, v));

    float fx = (u + 1.0f) * 0.5f * 15.0f;
    float fy = (v + 1.0f) * 0.5f * 15.0f;
    float x0f = floorf(fx), y0f = floorf(fy);
    float wx = fx - x0f, wy = fy - y0f;
    int px0 = (int)x0f; px0 = px0 < 0 ? 0 : (px0 > 15 ? 15 : px0);
    int py0 = (int)y0f; py0 = py0 < 0 ? 0 : (py0 > 15 ? 15 : py0);
    int px1 = px0 + 1 > 15 ? 15 : px0 + 1;
    int py1 = py0 + 1 > 15 ? 15 : py0 + 1;

    w00 = (1.0f - wx) * (1.0f - wy);
    w01 = wx * (1.0f - wy);
    w10 = (1.0f - wx) * wy;
    w11 = wx * wy;

    t00 = py0 * 16 + px0;
    t01 = py0 * 16 + px1;
    t10 = py1 * 16 + px0;
    t11 = py1 * 16 + px1;
}

__device__ __forceinline__ void gather_accum(
    const float4* __restrict__ cube4,
    int p0, int p1, int p2, int p3,
    float w0, float w1, float w2, float w3,
    int face, int t00, int t01, int t10, int t11,
    float w00, float w01, float w10, float w11,
    float& accr, float& accg, float& accb)
{
    int faceoff = face * 256;
    accr = 0.0f; accg = 0.0f; accb = 0.0f;
#pragma unroll
    for (int k = 0; k < 4; k++) {
        int   p  = (k == 0) ? p0 : (k == 1) ? p1 : (k == 2) ? p2 : p3;
        float wn = (k == 0) ? w0 : (k == 1) ? w1 : (k == 2) ? w2 : w3;
        int base = p * 1536 + faceoff;
        float4 v00 = cube4[base + t00];
        float4 v01 = cube4[base + t01];
        float4 v10 = cube4[base + t10];
        float4 v11 = cube4[base + t11];
        float r = fmaf(v00.x, w00, fmaf(v01.x, w01, fmaf(v10.x, w10, v11.x * w11)));
        float g = fmaf(v00.y, w00, fmaf(v01.y, w01, fmaf(v10.y, w10, v11.y * w11)));
        float b = fmaf(v00.z, w00, fmaf(v01.z, w01, fmaf(v10.z, w10, v11.z * w11)));
        accr = fmaf(wn, r, accr);
        accg = fmaf(wn, g, accg);
        accb = fmaf(wn, b, accb);
    }
}

// ---- repack cubemap (125,6,16,16,3) f32 -> float4-padded texels in ws ----
__global__ __launch_bounds__(256) void repack_kernel(
    const float* __restrict__ cube, float4* __restrict__ cube4)
{
    int t = blockIdx.x * blockDim.x + threadIdx.x;
    if (t >= NTEX) return;
    float4 v;
    v.x = cube[3 * t + 0];
    v.y = cube[3 * t + 1];
    v.z = cube[3 * t + 2];
    v.w = 0.0f;
    cube4[t] = v;
}

__global__ __launch_bounds__(256) void lp_pair(
    const float* __restrict__ xyz,
    const float* __restrict__ vdirs,
    const float4* __restrict__ cube4,
    float* __restrict__ out,
    int N, int NT)
{
    int t = blockIdx.x * blockDim.x + threadIdx.x;
    if (t >= NT) return;
    int ia = t;
    int ib = t + NT;
    bool hasB = ib < N;
    int ibc = hasB ? ib : ia;

    float xa = __builtin_nontemporal_load(&xyz[3 * ia + 0]);
    float ya = __builtin_nontemporal_load(&xyz[3 * ia + 1]);
    float za = __builtin_nontemporal_load(&xyz[3 * ia + 2]);
    float dxa = __builtin_nontemporal_load(&vdirs[3 * ia + 0]);
    float dya = __builtin_nontemporal_load(&vdirs[3 * ia + 1]);
    float dza = __builtin_nontemporal_load(&vdirs[3 * ia + 2]);

    float xb = __builtin_nontemporal_load(&xyz[3 * ibc + 0]);
    float yb = __builtin_nontemporal_load(&xyz[3 * ibc + 1]);
    float zb = __builtin_nontemporal_load(&xyz[3 * ibc + 2]);
    float dxb = __builtin_nontemporal_load(&vdirs[3 * ibc + 0]);
    float dyb = __builtin_nontemporal_load(&vdirs[3 * ibc + 1]);
    float dzb = __builtin_nontemporal_load(&vdirs[3 * ibc + 2]);

    // ---- per-dim setup ----
    float exA[3], eyA[3], ezA[3], exB[3], eyB[3], ezB[3];
    int sxA = dimprep(xa, exA), syA = dimprep(ya, eyA), szA = dimprep(za, ezA);
    int sxB = dimprep(xb, exB), syB = dimprep(yb, eyB), szB = dimprep(zb, ezB);
    int baseA = (sxA * 5 + syA) * 5 + szA;
    int baseB = (sxB * 5 + syB) * 5 + szB;

    float exyA[9], exyB[9];
#pragma unroll
    for (int a = 0; a < 3; a++)
#pragma unroll
        for (int b = 0; b < 3; b++) {
            exyA[a * 3 + b] = exA[a] + eyA[b];
            exyB[a * 3 + b] = exB[a] + eyB[b];
        }

    // ---- fused top-4 selection (27 candidates, ascending index, strict <) ----
    float s0A = 1e30f, s1A = 1e30f, s2A = 1e30f, s3A = 1e30f;
    float s0B = 1e30f, s1B = 1e30f, s2B = 1e30f, s3B = 1e30f;
    int k0A = 0, k1A = 0, k2A = 0, k3A = 0;
    int k0B = 0, k1B = 0, k2B = 0, k3B = 0;

#pragma unroll
    for (int ab = 0; ab < 9; ab++) {
#pragma unroll
        for (int c = 0; c < 3; c++) {
            const int lit = (ab / 3) * 25 + (ab % 3) * 5 + c;  // compile-time
            float dA = exyA[ab] + ezA[c];
            INSERT(dA, lit, s0A, s1A, s2A, s3A, k0A, k1A, k2A, k3A);
            float dB = exyB[ab] + ezB[c];
            INSERT(dB, lit, s0B, s1B, s2B, s3B, k0B, k1B, k2B, k3B);
        }
    }

    // ---- weights from dist = sqrt(d2) (continuous use only) ----
    float w0A = fastrcp(fastsqrt(s0A) + 1e-4f);
    float w1A = fastrcp(fastsqrt(s1A) + 1e-4f);
    float w2A = fastrcp(fastsqrt(s2A) + 1e-4f);
    float w3A = fastrcp(fastsqrt(s3A) + 1e-4f);
    float wiA = fastrcp(w0A + w1A + w2A + w3A);
    w0A *= wiA; w1A *= wiA; w2A *= wiA; w3A *= wiA;

    float w0B = fastrcp(fastsqrt(s0B) + 1e-4f);
    float w1B = fastrcp(fastsqrt(s1B) + 1e-4f);
    float w2B = fastrcp(fastsqrt(s2B) + 1e-4f);
    float w3B = fastrcp(fastsqrt(s3B) + 1e-4f);
    float wiB = fastrcp(w0B + w1B + w2B + w3B);
    w0B *= wiB; w1B *= wiB; w2B *= wiB; w3B *= wiB;

    // ---- uv/face (bit-identical to R2) ----
    int faceA, t00A, t01A, t10A, t11A, faceB, t00B, t01B, t10B, t11B;
    float w00A, w01A, w10A, w11A, w00B, w01B, w10B, w11B;
    uv_setup(dxa, dya, dza, faceA, t00A, t01A, t10A, t11A, w00A, w01A, w10A, w11A);
    uv_setup(dxb, dyb, dzb, faceB, t00B, t01B, t10B, t11B, w00B, w01B, w10B, w11B);

    // ---- gather + weighted sum ----
    float ra, ga, ba, rb, gb, bb;
    gather_accum(cube4, baseA + k0A, baseA + k1A, baseA + k2A, baseA + k3A,
                 w0A, w1A, w2A, w3A, faceA, t00A, t01A, t10A, t11A,
                 w00A, w01A, w10A, w11A, ra, ga, ba);
    gather_accum(cube4, baseB + k0B, baseB + k1B, baseB + k2B, baseB + k3B,
                 w0B, w1B, w2B, w3B, faceB, t00B, t01B, t10B, t11B,
                 w00B, w01B, w10B, w11B, rb, gb, bb);

    __builtin_nontemporal_store(ra, &out[3 * ia + 0]);
    __builtin_nontemporal_store(ga, &out[3 * ia + 1]);
    __builtin_nontemporal_store(ba, &out[3 * ia + 2]);
    if (hasB) {
        __builtin_nontemporal_store(rb, &out[3 * ib + 0]);
        __builtin_nontemporal_store(gb, &out[3 * ib + 1]);
        __builtin_nontemporal_store(bb, &out[3 * ib + 2]);
    }
}

extern "C" void kernel_launch(void* const* d_in, const int* in_sizes, int n_in,
                              void* d_out, int out_size, void* d_ws, size_t ws_size,
                              hipStream_t stream) {
    const float* xyz  = (const float*)d_in[0];
    const float* vd   = (const float*)d_in[1];
    const float* cube = (const float*)d_in[2];
    float* outp = (float*)d_out;
    int N = in_sizes[0] / 3;
    int NT = (N + 1) / 2;
    int blocks = (NT + 255) / 256;

    float4* cube4 = (float4*)d_ws;
    hipLaunchKernelGGL(repack_kernel, dim3((NTEX + 255) / 256), dim3(256), 0, stream,
                       cube, cube4);
    hipLaunchKernelGGL(lp_pair, dim3(blocks), dim3(256), 0, stream,
                       xyz, vd, cube4, outp, N, NT);
}

// Round 4
// 57.586 us; speedup vs baseline: 1.0217x; 1.0217x over previous
//
#include <hip/hip_runtime.h>
#include <math.h>

// LightingProbes R4: patch-precompute gather.
// Bottleneck identified in R1-R3: ~12-16 distinct 128B L2 lines fetched per
// point by the scattered bilinear gather (~2GB L2->L1 at ~34.5TB/s = ~58us,
// invariant across instruction-count changes). Fix: precompute per
// (face,py0,px0,probe) the 2x2 bilinear footprint as one 64B patch (4xfloat4,
// single cacheline). 4 patch reads/point => ~3.5-4 lines/point.
// Selection + bilinear math bit-identical to R3.

#define NTEX        192000            // 125*6*16*16 texels (fallback cube4)
#define NPATCH      192000            // 6*16*16*125 patches
#define PATCH_BYTES (NPATCH * 64)     // 12.288 MB

__device__ __forceinline__ float fastrcp(float x)  { return __builtin_amdgcn_rcpf(x); }
__device__ __forceinline__ float fastsqrt(float x) { return __builtin_amdgcn_sqrtf(x); }

__device__ __forceinline__ int dim_start(float v) {
    float f = (v + 3.0f) * (1.0f / 1.5f);
    int n = (int)floorf(f + 0.5f);
    n = n < 0 ? 0 : (n > 4 ? 4 : n);
    int s = n - 1;
    s = s < 0 ? 0 : (s > 2 ? 2 : s);
    return s;
}

__device__ __forceinline__ int dimprep(float v, float e[3]) {
    int s = dim_start(v);
    float p0 = fmaf(1.5f, (float)s, -3.0f);
    float d0 = v - p0;
    float d1 = d0 - 1.5f;
    float d2 = d1 - 1.5f;
    e[0] = d0 * d0; e[1] = d1 * d1; e[2] = d2 * d2;
    return s;
}

#define INSERT(d, L, s0, s1, s2, s3, k0, k1, k2, k3)                          \
    {                                                                         \
        bool lt = (d) < s3; s3 = lt ? (d) : s3; k3 = lt ? (L) : k3;           \
        { bool cb = s3 < s2; float nd = cb ? s3 : s2, xd = cb ? s2 : s3;      \
          int ni = cb ? k3 : k2, xi = cb ? k2 : k3;                           \
          s2 = nd; s3 = xd; k2 = ni; k3 = xi; }                               \
        { bool cb = s2 < s1; float nd = cb ? s2 : s1, xd = cb ? s1 : s2;      \
          int ni = cb ? k2 : k1, xi = cb ? k1 : k2;                           \
          s1 = nd; s2 = xd; k1 = ni; k2 = xi; }                               \
        { bool cb = s1 < s0; float nd = cb ? s1 : s0, xd = cb ? s0 : s1;      \
          int ni = cb ? k1 : k0, xi = cb ? k0 : k1;                           \
          s0 = nd; s1 = xd; k0 = ni; k1 = xi; }                               \
    }

// uv/face -> (face, t00 texel index, bilinear weights). Math bit-identical R3.
__device__ __forceinline__ void uv_setup(
    float dx, float dy, float dz,
    int& face, int& t00,
    float& w00, float& w01, float& w10, float& w11)
{
    float nrm = sqrtf(fmaf(dx, dx, fmaf(dy, dy, dz * dz)));
    nrm = fmaxf(nrm, 1e-12f);
    float inv = fastrcp(nrm);
    float ux = dx * inv, uy = dy * inv, uz = dz * inv;
    float ax = fabsf(ux), ay = fabsf(uy), az = fabsf(uz);

    bool xd = (ax >= ay) && (ax >= az);
    float den, un, vn;
    if (xd) {
        face = (ux > 0.0f) ? 0 : 1;
        den = ax; un = (ux > 0.0f) ? -uz : uz; vn = -uy;
    } else if (ay >= az) {
        face = (uy > 0.0f) ? 2 : 3;
        den = ay; un = ux; vn = (uy > 0.0f) ? uz : -uz;
    } else {
        face = (uz > 0.0f) ? 4 : 5;
        den = az; un = (uz > 0.0f) ? ux : -ux; vn = -uy;
    }
    float rden = fastrcp(den + 1e-8f);
    float u = un * rden;
    float v = vn * rden;
    u = fminf(1.0f, fmaxf(-1.0f, u));
    v = fminf(1.0f, fmaxf(-1.0f, v));

    float fx = (u + 1.0f) * 0.5f * 15.0f;
    float fy = (v + 1.0f) * 0.5f * 15.0f;
    float x0f = floorf(fx), y0f = floorf(fy);
    float wx = fx - x0f, wy = fy - y0f;
    int px0 = (int)x0f; px0 = px0 < 0 ? 0 : (px0 > 15 ? 15 : px0);
    int py0 = (int)y0f; py0 = py0 < 0 ? 0 : (py0 > 15 ? 15 : py0);

    w00 = (1.0f - wx) * (1.0f - wy);
    w01 = wx * (1.0f - wy);
    w10 = (1.0f - wx) * wy;
    w11 = wx * wy;

    t00 = py0 * 16 + px0;
}

// ---- build patch texture: patch[((face*256 + t00)*125 + p)] = 4 float4 ----
__global__ __launch_bounds__(256) void build_patches(
    const float* __restrict__ cube, float4* __restrict__ patches)
{
    int t = blockIdx.x * blockDim.x + threadIdx.x;
    if (t >= NPATCH) return;
    int p   = t % 125;
    int q   = t / 125;
    int px0 = q % 16; q /= 16;
    int py0 = q % 16;
    int face = q / 16;
    int px1 = px0 + 1 > 15 ? 15 : px0 + 1;
    int py1 = py0 + 1 > 15 ? 15 : py0 + 1;

    const float* f = cube + (p * 6 + face) * 768;   // 16*16*3
    int o00 = (py0 * 16 + px0) * 3;
    int o01 = (py0 * 16 + px1) * 3;
    int o10 = (py1 * 16 + px0) * 3;
    int o11 = (py1 * 16 + px1) * 3;

    float4* dst = patches + (size_t)t * 4;
    dst[0] = make_float4(f[o00], f[o00 + 1], f[o00 + 2], 0.0f);
    dst[1] = make_float4(f[o01], f[o01 + 1], f[o01 + 2], 0.0f);
    dst[2] = make_float4(f[o10], f[o10 + 1], f[o10 + 2], 0.0f);
    dst[3] = make_float4(f[o11], f[o11 + 1], f[o11 + 2], 0.0f);
}

__device__ __forceinline__ void gather_patch(
    const float4* __restrict__ patches,
    int p0, int p1, int p2, int p3,
    float w0, float w1, float w2, float w3,
    int face, int t00,
    float w00, float w01, float w10, float w11,
    float& accr, float& accg, float& accb)
{
    int cell = (face * 256 + t00) * 125;    // patch row for this (face,texel)
    accr = 0.0f; accg = 0.0f; accb = 0.0f;
#pragma unroll
    for (int k = 0; k < 4; k++) {
        int   p  = (k == 0) ? p0 : (k == 1) ? p1 : (k == 2) ? p2 : p3;
        float wn = (k == 0) ? w0 : (k == 1) ? w1 : (k == 2) ? w2 : w3;
        const float4* pp = patches + (size_t)(cell + p) * 4;
        float4 v00 = pp[0];
        float4 v01 = pp[1];
        float4 v10 = pp[2];
        float4 v11 = pp[3];
        float r = fmaf(v00.x, w00, fmaf(v01.x, w01, fmaf(v10.x, w10, v11.x * w11)));
        float g = fmaf(v00.y, w00, fmaf(v01.y, w01, fmaf(v10.y, w10, v11.y * w11)));
        float b = fmaf(v00.z, w00, fmaf(v01.z, w01, fmaf(v10.z, w10, v11.z * w11)));
        accr = fmaf(wn, r, accr);
        accg = fmaf(wn, g, accg);
        accb = fmaf(wn, b, accb);
    }
}

__global__ __launch_bounds__(256) void lp_pair_patch(
    const float* __restrict__ xyz,
    const float* __restrict__ vdirs,
    const float4* __restrict__ patches,
    float* __restrict__ out,
    int N, int NT)
{
    int t = blockIdx.x * blockDim.x + threadIdx.x;
    if (t >= NT) return;
    int ia = t;
    int ib = t + NT;
    bool hasB = ib < N;
    int ibc = hasB ? ib : ia;

    float xa = __builtin_nontemporal_load(&xyz[3 * ia + 0]);
    float ya = __builtin_nontemporal_load(&xyz[3 * ia + 1]);
    float za = __builtin_nontemporal_load(&xyz[3 * ia + 2]);
    float dxa = __builtin_nontemporal_load(&vdirs[3 * ia + 0]);
    float dya = __builtin_nontemporal_load(&vdirs[3 * ia + 1]);
    float dza = __builtin_nontemporal_load(&vdirs[3 * ia + 2]);

    float xb = __builtin_nontemporal_load(&xyz[3 * ibc + 0]);
    float yb = __builtin_nontemporal_load(&xyz[3 * ibc + 1]);
    float zb = __builtin_nontemporal_load(&xyz[3 * ibc + 2]);
    float dxb = __builtin_nontemporal_load(&vdirs[3 * ibc + 0]);
    float dyb = __builtin_nontemporal_load(&vdirs[3 * ibc + 1]);
    float dzb = __builtin_nontemporal_load(&vdirs[3 * ibc + 2]);

    float exA[3], eyA[3], ezA[3], exB[3], eyB[3], ezB[3];
    int sxA = dimprep(xa, exA), syA = dimprep(ya, eyA), szA = dimprep(za, ezA);
    int sxB = dimprep(xb, exB), syB = dimprep(yb, eyB), szB = dimprep(zb, ezB);
    int baseA = (sxA * 5 + syA) * 5 + szA;
    int baseB = (sxB * 5 + syB) * 5 + szB;

    float exyA[9], exyB[9];
#pragma unroll
    for (int a = 0; a < 3; a++)
#pragma unroll
        for (int b = 0; b < 3; b++) {
            exyA[a * 3 + b] = exA[a] + eyA[b];
            exyB[a * 3 + b] = exB[a] + eyB[b];
        }

    float s0A = 1e30f, s1A = 1e30f, s2A = 1e30f, s3A = 1e30f;
    float s0B = 1e30f, s1B = 1e30f, s2B = 1e30f, s3B = 1e30f;
    int k0A = 0, k1A = 0, k2A = 0, k3A = 0;
    int k0B = 0, k1B = 0, k2B = 0, k3B = 0;

#pragma unroll
    for (int ab = 0; ab < 9; ab++) {
#pragma unroll
        for (int c = 0; c < 3; c++) {
            const int lit = (ab / 3) * 25 + (ab % 3) * 5 + c;
            float dA = exyA[ab] + ezA[c];
            INSERT(dA, lit, s0A, s1A, s2A, s3A, k0A, k1A, k2A, k3A);
            float dB = exyB[ab] + ezB[c];
            INSERT(dB, lit, s0B, s1B, s2B, s3B, k0B, k1B, k2B, k3B);
        }
    }

    float w0A = fastrcp(fastsqrt(s0A) + 1e-4f);
    float w1A = fastrcp(fastsqrt(s1A) + 1e-4f);
    float w2A = fastrcp(fastsqrt(s2A) + 1e-4f);
    float w3A = fastrcp(fastsqrt(s3A) + 1e-4f);
    float wiA = fastrcp(w0A + w1A + w2A + w3A);
    w0A *= wiA; w1A *= wiA; w2A *= wiA; w3A *= wiA;

    float w0B = fastrcp(fastsqrt(s0B) + 1e-4f);
    float w1B = fastrcp(fastsqrt(s1B) + 1e-4f);
    float w2B = fastrcp(fastsqrt(s2B) + 1e-4f);
    float w3B = fastrcp(fastsqrt(s3B) + 1e-4f);
    float wiB = fastrcp(w0B + w1B + w2B + w3B);
    w0B *= wiB; w1B *= wiB; w2B *= wiB; w3B *= wiB;

    int faceA, t00A, faceB, t00B;
    float w00A, w01A, w10A, w11A, w00B, w01B, w10B, w11B;
    uv_setup(dxa, dya, dza, faceA, t00A, w00A, w01A, w10A, w11A);
    uv_setup(dxb, dyb, dzb, faceB, t00B, w00B, w01B, w10B, w11B);

    float ra, ga, ba, rb, gb, bb;
    gather_patch(patches, baseA + k0A, baseA + k1A, baseA + k2A, baseA + k3A,
                 w0A, w1A, w2A, w3A, faceA, t00A, w00A, w01A, w10A, w11A, ra, ga, ba);
    gather_patch(patches, baseB + k0B, baseB + k1B, baseB + k2B, baseB + k3B,
                 w0B, w1B, w2B, w3B, faceB, t00B, w00B, w01B, w10B, w11B, rb, gb, bb);

    __builtin_nontemporal_store(ra, &out[3 * ia + 0]);
    __builtin_nontemporal_store(ga, &out[3 * ia + 1]);
    __builtin_nontemporal_store(ba, &out[3 * ia + 2]);
    if (hasB) {
        __builtin_nontemporal_store(rb, &out[3 * ib + 0]);
        __builtin_nontemporal_store(gb, &out[3 * ib + 1]);
        __builtin_nontemporal_store(bb, &out[3 * ib + 2]);
    }
}

// ================= fallback path (R3, cube4 texel layout) =================
__global__ __launch_bounds__(256) void repack_kernel(
    const float* __restrict__ cube, float4* __restrict__ cube4)
{
    int t = blockIdx.x * blockDim.x + threadIdx.x;
    if (t >= NTEX) return;
    cube4[t] = make_float4(cube[3 * t], cube[3 * t + 1], cube[3 * t + 2], 0.0f);
}

__global__ __launch_bounds__(256) void lp_pair_tex(
    const float* __restrict__ xyz,
    const float* __restrict__ vdirs,
    const float4* __restrict__ cube4,
    float* __restrict__ out,
    int N, int NT)
{
    int t = blockIdx.x * blockDim.x + threadIdx.x;
    if (t >= NT) return;
    int ia = t, ib = t + NT;
    bool hasB = ib < N;
    int ibc = hasB ? ib : ia;

    float xa = xyz[3 * ia], ya = xyz[3 * ia + 1], za = xyz[3 * ia + 2];
    float dxa = vdirs[3 * ia], dya = vdirs[3 * ia + 1], dza = vdirs[3 * ia + 2];
    float xb = xyz[3 * ibc], yb = xyz[3 * ibc + 1], zb = xyz[3 * ibc + 2];
    float dxb = vdirs[3 * ibc], dyb = vdirs[3 * ibc + 1], dzb = vdirs[3 * ibc + 2];

    float exA[3], eyA[3], ezA[3], exB[3], eyB[3], ezB[3];
    int sxA = dimprep(xa, exA), syA = dimprep(ya, eyA), szA = dimprep(za, ezA);
    int sxB = dimprep(xb, exB), syB = dimprep(yb, eyB), szB = dimprep(zb, ezB);
    int baseA = (sxA * 5 + syA) * 5 + szA;
    int baseB = (sxB * 5 + syB) * 5 + szB;

    float exyA[9], exyB[9];
#pragma unroll
    for (int a = 0; a < 3; a++)
#pragma unroll
        for (int b = 0; b < 3; b++) {
            exyA[a * 3 + b] = exA[a] + eyA[b];
            exyB[a * 3 + b] = exB[a] + eyB[b];
        }

    float s0A = 1e30f, s1A = 1e30f, s2A = 1e30f, s3A = 1e30f;
    float s0B = 1e30f, s1B = 1e30f, s2B = 1e30f, s3B = 1e30f;
    int k0A = 0, k1A = 0, k2A = 0, k3A = 0, k0B = 0, k1B = 0, k2B = 0, k3B = 0;
#pragma unroll
    for (int ab = 0; ab < 9; ab++)
#pragma unroll
        for (int c = 0; c < 3; c++) {
            const int lit = (ab / 3) * 25 + (ab % 3) * 5 + c;
            float dA = exyA[ab] + ezA[c];
            INSERT(dA, lit, s0A, s1A, s2A, s3A, k0A, k1A, k2A, k3A);
            float dB = exyB[ab] + ezB[c];
            INSERT(dB, lit, s0B, s1B, s2B, s3B, k0B, k1B, k2B, k3B);
        }

    float w0A = fastrcp(fastsqrt(s0A) + 1e-4f);
    float w1A = fastrcp(fastsqrt(s1A) + 1e-4f);
    float w2A = fastrcp(fastsqrt(s2A) + 1e-4f);
    float w3A = fastrcp(fastsqrt(s3A) + 1e-4f);
    float wiA = fastrcp(w0A + w1A + w2A + w3A);
    w0A *= wiA; w1A *= wiA; w2A *= wiA; w3A *= wiA;
    float w0B = fastrcp(fastsqrt(s0B) + 1e-4f);
    float w1B = fastrcp(fastsqrt(s1B) + 1e-4f);
    float w2B = fastrcp(fastsqrt(s2B) + 1e-4f);
    float w3B = fastrcp(fastsqrt(s3B) + 1e-4f);
    float wiB = fastrcp(w0B + w1B + w2B + w3B);
    w0B *= wiB; w1B *= wiB; w2B *= wiB; w3B *= wiB;

    int faceA, t00A, faceB, t00B;
    float w00A, w01A, w10A, w11A, w00B, w01B, w10B, w11B;
    uv_setup(dxa, dya, dza, faceA, t00A, w00A, w01A, w10A, w11A);
    uv_setup(dxb, dyb, dzb, faceB, t00B, w00B, w01B, w10B, w11B);

    // reconstruct t01/t10/t11 from t00 (same clamping as R3)
    int px0A = t00A & 15, py0A = t00A >> 4;
    int px1A = px0A + 1 > 15 ? 15 : px0A + 1, py1A = py0A + 1 > 15 ? 15 : py0A + 1;
    int t01A = py0A * 16 + px1A, t10A = py1A * 16 + px0A, t11A = py1A * 16 + px1A;
    int px0B = t00B & 15, py0B = t00B >> 4;
    int px1B = px0B + 1 > 15 ? 15 : px0B + 1, py1B = py0B + 1 > 15 ? 15 : py0B + 1;
    int t01B = py0B * 16 + px1B, t10B = py1B * 16 + px0B, t11B = py1B * 16 + px1B;

    float accA[3] = {0, 0, 0}, accB[3] = {0, 0, 0};
#pragma unroll
    for (int k = 0; k < 4; k++) {
        int   pA = baseA + ((k == 0) ? k0A : (k == 1) ? k1A : (k == 2) ? k2A : k3A);
        float wA = (k == 0) ? w0A : (k == 1) ? w1A : (k == 2) ? w2A : w3A;
        int bA = pA * 1536 + faceA * 256;
        float4 a00 = cube4[bA + t00A], a01 = cube4[bA + t01A];
        float4 a10 = cube4[bA + t10A], a11 = cube4[bA + t11A];
        accA[0] = fmaf(wA, fmaf(a00.x, w00A, fmaf(a01.x, w01A, fmaf(a10.x, w10A, a11.x * w11A))), accA[0]);
        accA[1] = fmaf(wA, fmaf(a00.y, w00A, fmaf(a01.y, w01A, fmaf(a10.y, w10A, a11.y * w11A))), accA[1]);
        accA[2] = fmaf(wA, fmaf(a00.z, w00A, fmaf(a01.z, w01A, fmaf(a10.z, w10A, a11.z * w11A))), accA[2]);
        int   pB = baseB + ((k == 0) ? k0B : (k == 1) ? k1B : (k == 2) ? k2B : k3B);
        float wB = (k == 0) ? w0B : (k == 1) ? w1B : (k == 2) ? w2B : w3B;
        int bB = pB * 1536 + faceB * 256;
        float4 b00 = cube4[bB + t00B], b01 = cube4[bB + t01B];
        float4 b10 = cube4[bB + t10B], b11 = cube4[bB + t11B];
        accB[0] = fmaf(wB, fmaf(b00.x, w00B, fmaf(b01.x, w01B, fmaf(b10.x, w10B, b11.x * w11B))), accB[0]);
        accB[1] = fmaf(wB, fmaf(b00.y, w00B, fmaf(b01.y, w01B, fmaf(b10.y, w10B, b11.y * w11B))), accB[1]);
        accB[2] = fmaf(wB, fmaf(b00.z, w00B, fmaf(b01.z, w01B, fmaf(b10.z, w10B, b11.z * w11B))), accB[2]);
    }

    out[3 * ia] = accA[0]; out[3 * ia + 1] = accA[1]; out[3 * ia + 2] = accA[2];
    if (hasB) { out[3 * ib] = accB[0]; out[3 * ib + 1] = accB[1]; out[3 * ib + 2] = accB[2]; }
}

extern "C" void kernel_launch(void* const* d_in, const int* in_sizes, int n_in,
                              void* d_out, int out_size, void* d_ws, size_t ws_size,
                              hipStream_t stream) {
    const float* xyz  = (const float*)d_in[0];
    const float* vd   = (const float*)d_in[1];
    const float* cube = (const float*)d_in[2];
    float* outp = (float*)d_out;
    int N = in_sizes[0] / 3;
    int NT = (N + 1) / 2;
    int blocks = (NT + 255) / 256;

    if (ws_size >= (size_t)PATCH_BYTES) {
        float4* patches = (float4*)d_ws;
        hipLaunchKernelGGL(build_patches, dim3((NPATCH + 255) / 256), dim3(256), 0, stream,
                           cube, patches);
        hipLaunchKernelGGL(lp_pair_patch, dim3(blocks), dim3(256), 0, stream,
                           xyz, vd, patches, outp, N, NT);
    } else {
        float4* cube4 = (float4*)d_ws;
        hipLaunchKernelGGL(repack_kernel, dim3((NTEX + 255) / 256), dim3(256), 0, stream,
                           cube, cube4);
        hipLaunchKernelGGL(lp_pair_tex, dim3(blocks), dim3(256), 0, stream,
                           xyz, vd, cube4, outp, N, NT);
    }
}

// Round 5
// 43.230 us; speedup vs baseline: 1.3610x; 1.3321x over previous
//
#include <hip/hip_runtime.h>
#include <hip/hip_fp16.h>
#include <math.h>

// LightingProbes R5: coalesced LDS-staged streaming I/O + f16 32B patches.
// Selection (27-cand separable d2, strict-<) and uv math bit-identical to R4.

#define NPATCH      192000            // 6*16*16*125 patches
#define PATCH_HALF  16                // 16 halfs = 32B per patch
#define PATCH_BYTES ((size_t)NPATCH * PATCH_HALF * 2)   // 6.144 MB

typedef float vf4 __attribute__((ext_vector_type(4)));
typedef unsigned int u32x4 __attribute__((ext_vector_type(4)));
typedef unsigned int u32x2 __attribute__((ext_vector_type(2)));

__device__ __forceinline__ float fastrcp(float x)  { return __builtin_amdgcn_rcpf(x); }
__device__ __forceinline__ float fastsqrt(float x) { return __builtin_amdgcn_sqrtf(x); }

__device__ __forceinline__ void up2(unsigned u, float& a, float& b) {
    __half2 h;
    *(unsigned*)&h = u;
    float2 f = __half22float2(h);
    a = f.x; b = f.y;
}

__device__ __forceinline__ int dim_start(float v) {
    float f = (v + 3.0f) * (1.0f / 1.5f);
    int n = (int)floorf(f + 0.5f);
    n = n < 0 ? 0 : (n > 4 ? 4 : n);
    int s = n - 1;
    s = s < 0 ? 0 : (s > 2 ? 2 : s);
    return s;
}

__device__ __forceinline__ int dimprep(float v, float e[3]) {
    int s = dim_start(v);
    float p0 = fmaf(1.5f, (float)s, -3.0f);
    float d0 = v - p0;
    float d1 = d0 - 1.5f;
    float d2 = d1 - 1.5f;
    e[0] = d0 * d0; e[1] = d1 * d1; e[2] = d2 * d2;
    return s;
}

#define INSERT(d, L, s0, s1, s2, s3, k0, k1, k2, k3)                          \
    {                                                                         \
        bool lt = (d) < s3; s3 = lt ? (d) : s3; k3 = lt ? (L) : k3;           \
        { bool cb = s3 < s2; float nd = cb ? s3 : s2, xd = cb ? s2 : s3;      \
          int ni = cb ? k3 : k2, xi = cb ? k2 : k3;                           \
          s2 = nd; s3 = xd; k2 = ni; k3 = xi; }                               \
        { bool cb = s2 < s1; float nd = cb ? s2 : s1, xd = cb ? s1 : s2;      \
          int ni = cb ? k2 : k1, xi = cb ? k1 : k2;                           \
          s1 = nd; s2 = xd; k1 = ni; k2 = xi; }                               \
        { bool cb = s1 < s0; float nd = cb ? s1 : s0, xd = cb ? s0 : s1;      \
          int ni = cb ? k1 : k0, xi = cb ? k0 : k1;                           \
          s0 = nd; s1 = xd; k0 = ni; k1 = xi; }                               \
    }

// uv/face -> (face, t00, bilinear weights). Math bit-identical to R4.
__device__ __forceinline__ void uv_setup(
    float dx, float dy, float dz,
    int& face, int& t00,
    float& w00, float& w01, float& w10, float& w11)
{
    float nrm = sqrtf(fmaf(dx, dx, fmaf(dy, dy, dz * dz)));
    nrm = fmaxf(nrm, 1e-12f);
    float inv = fastrcp(nrm);
    float ux = dx * inv, uy = dy * inv, uz = dz * inv;
    float ax = fabsf(ux), ay = fabsf(uy), az = fabsf(uz);

    bool xd = (ax >= ay) && (ax >= az);
    float den, un, vn;
    if (xd) {
        face = (ux > 0.0f) ? 0 : 1;
        den = ax; un = (ux > 0.0f) ? -uz : uz; vn = -uy;
    } else if (ay >= az) {
        face = (uy > 0.0f) ? 2 : 3;
        den = ay; un = ux; vn = (uy > 0.0f) ? uz : -uz;
    } else {
        face = (uz > 0.0f) ? 4 : 5;
        den = az; un = (uz > 0.0f) ? ux : -ux; vn = -uy;
    }
    float rden = fastrcp(den + 1e-8f);
    float u = un * rden;
    float v = vn * rden;
    u = fminf(1.0f, fmaxf(-1.0f, u));
    v = fminf(1.0f, fmaxf(-1.0f, v));

    float fx = (u + 1.0f) * 0.5f * 15.0f;
    float fy = (v + 1.0f) * 0.5f * 15.0f;
    float x0f = floorf(fx), y0f = floorf(fy);
    float wx = fx - x0f, wy = fy - y0f;
    int px0 = (int)x0f; px0 = px0 < 0 ? 0 : (px0 > 15 ? 15 : px0);
    int py0 = (int)y0f; py0 = py0 < 0 ? 0 : (py0 > 15 ? 15 : py0);

    w00 = (1.0f - wx) * (1.0f - wy);
    w01 = wx * (1.0f - wy);
    w10 = (1.0f - wx) * wy;
    w11 = wx * wy;

    t00 = py0 * 16 + px0;
}

// ---- build f16 patches: patch[((face*256+t00)*125 + p)] = 12 halfs + pad ----
__global__ __launch_bounds__(256) void build_patches_f16(
    const float* __restrict__ cube, unsigned int* __restrict__ patches)
{
    int t = blockIdx.x * blockDim.x + threadIdx.x;
    if (t >= NPATCH) return;
    int p   = t % 125;
    int q   = t / 125;
    int px0 = q % 16; q /= 16;
    int py0 = q % 16;
    int face = q / 16;
    int px1 = px0 + 1 > 15 ? 15 : px0 + 1;
    int py1 = py0 + 1 > 15 ? 15 : py0 + 1;

    const float* f = cube + (p * 6 + face) * 768;
    int o00 = (py0 * 16 + px0) * 3;
    int o01 = (py0 * 16 + px1) * 3;
    int o10 = (py1 * 16 + px0) * 3;
    int o11 = (py1 * 16 + px1) * 3;

    float v[12];
    v[0] = f[o00]; v[1] = f[o00 + 1]; v[2] = f[o00 + 2];
    v[3] = f[o01]; v[4] = f[o01 + 1]; v[5] = f[o01 + 2];
    v[6] = f[o10]; v[7] = f[o10 + 1]; v[8] = f[o10 + 2];
    v[9] = f[o11]; v[10] = f[o11 + 1]; v[11] = f[o11 + 2];

    unsigned u[8];
#pragma unroll
    for (int j = 0; j < 6; j++) {
        __half a = __float2half(v[2 * j]);
        __half b = __float2half(v[2 * j + 1]);
        u[j] = (unsigned)__half_as_ushort(a) | ((unsigned)__half_as_ushort(b) << 16);
    }
    u[6] = 0; u[7] = 0;

    u32x4* dst = (u32x4*)(patches + (size_t)t * 8);
    u32x4 a = {u[0], u[1], u[2], u[3]};
    u32x4 b = {u[4], u[5], u[6], u[7]};
    dst[0] = a;
    dst[1] = b;
}

__global__ __launch_bounds__(256) void lp_f16(
    const float* __restrict__ xyz,
    const float* __restrict__ vdirs,
    const unsigned int* __restrict__ patches,
    float* __restrict__ out,
    int N)
{
    __shared__ float sh[1536];          // [0..767] xyz (later reused for out), [768..1535] dirs

    int tid = threadIdx.x;
    int b0  = blockIdx.x * 256;
    int nPts = N - b0; nPts = nPts > 256 ? 256 : nPts;
    int nflt = nPts * 3;                // multiple of 4 for N=1e6 (tail=64 pts)
    int base4 = (b0 * 3) >> 2;          // b0*3 divisible by 4

    const vf4* x4 = (const vf4*)xyz;
    const vf4* d4 = (const vf4*)vdirs;
    if (tid * 4 < nflt) {
        vf4 vx = __builtin_nontemporal_load(&x4[base4 + tid]);
        ((vf4*)sh)[tid] = vx;
        vf4 vd = __builtin_nontemporal_load(&d4[base4 + tid]);
        ((vf4*)(sh + 768))[tid] = vd;
    }
    __syncthreads();

    float r = 0.0f, g = 0.0f, b = 0.0f;
    if (tid < nPts) {
        float x  = sh[3 * tid + 0];
        float y  = sh[3 * tid + 1];
        float z  = sh[3 * tid + 2];
        float dx = sh[768 + 3 * tid + 0];
        float dy = sh[768 + 3 * tid + 1];
        float dz = sh[768 + 3 * tid + 2];

        // ---- selection: 27 candidates, separable d2 (bit-identical to R4) ----
        float ex[3], ey[3], ez[3];
        int sx = dimprep(x, ex), sy = dimprep(y, ey), sz = dimprep(z, ez);
        int basep = (sx * 5 + sy) * 5 + sz;

        float exy[9];
#pragma unroll
        for (int a = 0; a < 3; a++)
#pragma unroll
            for (int bb = 0; bb < 3; bb++)
                exy[a * 3 + bb] = ex[a] + ey[bb];

        float s0 = 1e30f, s1 = 1e30f, s2 = 1e30f, s3 = 1e30f;
        int k0 = 0, k1 = 0, k2 = 0, k3 = 0;
#pragma unroll
        for (int ab = 0; ab < 9; ab++)
#pragma unroll
            for (int c = 0; c < 3; c++) {
                const int lit = (ab / 3) * 25 + (ab % 3) * 5 + c;
                float d = exy[ab] + ez[c];
                INSERT(d, lit, s0, s1, s2, s3, k0, k1, k2, k3);
            }

        float w0 = fastrcp(fastsqrt(s0) + 1e-4f);
        float w1 = fastrcp(fastsqrt(s1) + 1e-4f);
        float w2 = fastrcp(fastsqrt(s2) + 1e-4f);
        float w3 = fastrcp(fastsqrt(s3) + 1e-4f);
        float wi = fastrcp(w0 + w1 + w2 + w3);
        w0 *= wi; w1 *= wi; w2 *= wi; w3 *= wi;

        int face, t00;
        float w00, w01, w10, w11;
        uv_setup(dx, dy, dz, face, t00, w00, w01, w10, w11);

        int cell = (face * 256 + t00) * 125;
#pragma unroll
        for (int k = 0; k < 4; k++) {
            int   p  = (k == 0) ? k0 : (k == 1) ? k1 : (k == 2) ? k2 : k3;
            float wn = (k == 0) ? w0 : (k == 1) ? w1 : (k == 2) ? w2 : w3;
            const unsigned* pp = patches + (size_t)(cell + basep + p) * 8;
            u32x4 lo = *(const u32x4*)pp;
            u32x2 hi = *(const u32x2*)(pp + 4);
            float r00, g00, b00, r01, g01, b01, r10, g10, b10, r11, g11, b11;
            up2(lo.x, r00, g00);
            up2(lo.y, b00, r01);
            up2(lo.z, g01, b01);
            up2(lo.w, r10, g10);
            up2(hi.x, b10, r11);
            up2(hi.y, g11, b11);
            float rr = fmaf(r00, w00, fmaf(r01, w01, fmaf(r10, w10, r11 * w11)));
            float gg = fmaf(g00, w00, fmaf(g01, w01, fmaf(g10, w10, g11 * w11)));
            float bv = fmaf(b00, w00, fmaf(b01, w01, fmaf(b10, w10, b11 * w11)));
            r = fmaf(wn, rr, r);
            g = fmaf(wn, gg, g);
            b = fmaf(wn, bv, b);
        }
    }

    __syncthreads();                    // all reads of sh done before reuse
    if (tid < nPts) {
        sh[3 * tid + 0] = r;
        sh[3 * tid + 1] = g;
        sh[3 * tid + 2] = b;
    }
    __syncthreads();
    if (tid * 4 < nflt) {
        vf4* o4 = (vf4*)out;
        __builtin_nontemporal_store(((vf4*)sh)[tid], &o4[base4 + tid]);
    }
}

extern "C" void kernel_launch(void* const* d_in, const int* in_sizes, int n_in,
                              void* d_out, int out_size, void* d_ws, size_t ws_size,
                              hipStream_t stream) {
    const float* xyz  = (const float*)d_in[0];
    const float* vd   = (const float*)d_in[1];
    const float* cube = (const float*)d_in[2];
    float* outp = (float*)d_out;
    int N = in_sizes[0] / 3;
    int blocks = (N + 255) / 256;

    unsigned int* patches = (unsigned int*)d_ws;   // 6.144 MB (ws >= 12.3MB proven in R4)
    hipLaunchKernelGGL(build_patches_f16, dim3((NPATCH + 255) / 256), dim3(256), 0, stream,
                       cube, patches);
    hipLaunchKernelGGL(lp_f16, dim3(blocks), dim3(256), 0, stream,
                       xyz, vd, patches, outp, N);
}

// Round 6
// 41.460 us; speedup vs baseline: 1.4191x; 1.0427x over previous
//
#include <hip/hip_runtime.h>
#include <hip/hip_fp16.h>
#include <math.h>

// LightingProbes R6: 10-candidate separable top-4 selection (rank-space
// domination bound), stable per-dim sort-3 preserves index tie-breaks.
// I/O staging + f16 32B patch gather bit-identical to R5.

#define NPATCH      192000            // 6*16*16*125 patches
#define PATCH_BYTES ((size_t)NPATCH * 32)   // 6.144 MB

typedef float vf4 __attribute__((ext_vector_type(4)));
typedef unsigned int u32x4 __attribute__((ext_vector_type(4)));
typedef unsigned int u32x2 __attribute__((ext_vector_type(2)));

__device__ __forceinline__ float fastrcp(float x)  { return __builtin_amdgcn_rcpf(x); }
__device__ __forceinline__ float fastsqrt(float x) { return __builtin_amdgcn_sqrtf(x); }

__device__ __forceinline__ void up2(unsigned u, float& a, float& b) {
    __half2 h;
    *(unsigned*)&h = u;
    float2 f = __half22float2(h);
    a = f.x; b = f.y;
}

// per-dim: 3 candidate coords (s..s+2), squared errors sorted ascending
// (stable, strict < : ties keep lower coord index -> matches reference
// lower-probe-index tie-break). Outputs sorted errors e0<=e1<=e2 and the
// corresponding absolute coord indices c0,c1,c2.
__device__ __forceinline__ void dimsort(float v,
    float& e0, float& e1, float& e2, int& c0, int& c1, int& c2)
{
    float f = (v + 3.0f) * (1.0f / 1.5f);
    int n = (int)floorf(f + 0.5f);
    n = n < 0 ? 0 : (n > 4 ? 4 : n);
    int s = n - 1;
    s = s < 0 ? 0 : (s > 2 ? 2 : s);

    float p0 = fmaf(1.5f, (float)s, -3.0f);
    float d0 = v - p0;
    float d1 = d0 - 1.5f;
    float d2 = d1 - 1.5f;
    float a0 = d0 * d0, a1 = d1 * d1, a2 = d2 * d2;
    int j0 = s, j1 = s + 1, j2 = s + 2;

    {   bool sw = a1 < a0;
        float ta = sw ? a1 : a0, tb = sw ? a0 : a1;
        int   ua = sw ? j1 : j0, ub = sw ? j0 : j1;
        a0 = ta; a1 = tb; j0 = ua; j1 = ub; }
    {   bool sw = a2 < a1;
        float ta = sw ? a2 : a1, tb = sw ? a1 : a2;
        int   ua = sw ? j2 : j1, ub = sw ? j1 : j2;
        a1 = ta; a2 = tb; j1 = ua; j2 = ub; }
    {   bool sw = a1 < a0;
        float ta = sw ? a1 : a0, tb = sw ? a0 : a1;
        int   ua = sw ? j1 : j0, ub = sw ? j0 : j1;
        a0 = ta; a1 = tb; j0 = ua; j1 = ub; }

    e0 = a0; e1 = a1; e2 = a2;
    c0 = j0; c1 = j1; c2 = j2;
}

#define INSERT(d, L, s0, s1, s2, s3, k0, k1, k2, k3)                          \
    {                                                                         \
        bool lt = (d) < s3; s3 = lt ? (d) : s3; k3 = lt ? (L) : k3;           \
        { bool cb = s3 < s2; float nd = cb ? s3 : s2, xd = cb ? s2 : s3;      \
          int ni = cb ? k3 : k2, xi = cb ? k2 : k3;                           \
          s2 = nd; s3 = xd; k2 = ni; k3 = xi; }                               \
        { bool cb = s2 < s1; float nd = cb ? s2 : s1, xd = cb ? s1 : s2;      \
          int ni = cb ? k2 : k1, xi = cb ? k1 : k2;                           \
          s1 = nd; s2 = xd; k1 = ni; k2 = xi; }                               \
        { bool cb = s1 < s0; float nd = cb ? s1 : s0, xd = cb ? s0 : s1;      \
          int ni = cb ? k1 : k0, xi = cb ? k0 : k1;                           \
          s0 = nd; s1 = xd; k0 = ni; k1 = xi; }                               \
    }

// uv/face -> (face, t00, bilinear weights). Math bit-identical to R5.
__device__ __forceinline__ void uv_setup(
    float dx, float dy, float dz,
    int& face, int& t00,
    float& w00, float& w01, float& w10, float& w11)
{
    float nrm = sqrtf(fmaf(dx, dx, fmaf(dy, dy, dz * dz)));
    nrm = fmaxf(nrm, 1e-12f);
    float inv = fastrcp(nrm);
    float ux = dx * inv, uy = dy * inv, uz = dz * inv;
    float ax = fabsf(ux), ay = fabsf(uy), az = fabsf(uz);

    bool xd = (ax >= ay) && (ax >= az);
    float den, un, vn;
    if (xd) {
        face = (ux > 0.0f) ? 0 : 1;
        den = ax; un = (ux > 0.0f) ? -uz : uz; vn = -uy;
    } else if (ay >= az) {
        face = (uy > 0.0f) ? 2 : 3;
        den = ay; un = ux; vn = (uy > 0.0f) ? uz : -uz;
    } else {
        face = (uz > 0.0f) ? 4 : 5;
        den = az; un = (uz > 0.0f) ? ux : -ux; vn = -uy;
    }
    float rden = fastrcp(den + 1e-8f);
    float u = un * rden;
    float v = vn * rden;
    u = fminf(1.0f, fmaxf(-1.0f, u));
    v = fminf(1.0f, fmaxf(-1.0f, v));

    float fx = (u + 1.0f) * 0.5f * 15.0f;
    float fy = (v + 1.0f) * 0.5f * 15.0f;
    float x0f = floorf(fx), y0f = floorf(fy);
    float wx = fx - x0f, wy = fy - y0f;
    int px0 = (int)x0f; px0 = px0 < 0 ? 0 : (px0 > 15 ? 15 : px0);
    int py0 = (int)y0f; py0 = py0 < 0 ? 0 : (py0 > 15 ? 15 : py0);

    w00 = (1.0f - wx) * (1.0f - wy);
    w01 = wx * (1.0f - wy);
    w10 = (1.0f - wx) * wy;
    w11 = wx * wy;

    t00 = py0 * 16 + px0;
}

// ---- build f16 patches: patch[((face*256+t00)*125 + p)] = 12 halfs + pad ----
__global__ __launch_bounds__(256) void build_patches_f16(
    const float* __restrict__ cube, unsigned int* __restrict__ patches)
{
    int t = blockIdx.x * blockDim.x + threadIdx.x;
    if (t >= NPATCH) return;
    int p   = t % 125;
    int q   = t / 125;
    int px0 = q % 16; q /= 16;
    int py0 = q % 16;
    int face = q / 16;
    int px1 = px0 + 1 > 15 ? 15 : px0 + 1;
    int py1 = py0 + 1 > 15 ? 15 : py0 + 1;

    const float* f = cube + (p * 6 + face) * 768;
    int o00 = (py0 * 16 + px0) * 3;
    int o01 = (py0 * 16 + px1) * 3;
    int o10 = (py1 * 16 + px0) * 3;
    int o11 = (py1 * 16 + px1) * 3;

    float v[12];
    v[0] = f[o00]; v[1]  = f[o00 + 1]; v[2]  = f[o00 + 2];
    v[3] = f[o01]; v[4]  = f[o01 + 1]; v[5]  = f[o01 + 2];
    v[6] = f[o10]; v[7]  = f[o10 + 1]; v[8]  = f[o10 + 2];
    v[9] = f[o11]; v[10] = f[o11 + 1]; v[11] = f[o11 + 2];

    unsigned u[8];
#pragma unroll
    for (int j = 0; j < 6; j++) {
        __half a = __float2half(v[2 * j]);
        __half b = __float2half(v[2 * j + 1]);
        u[j] = (unsigned)__half_as_ushort(a) | ((unsigned)__half_as_ushort(b) << 16);
    }
    u[6] = 0; u[7] = 0;

    u32x4* dst = (u32x4*)(patches + (size_t)t * 8);
    u32x4 a = {u[0], u[1], u[2], u[3]};
    u32x4 b = {u[4], u[5], u[6], u[7]};
    dst[0] = a;
    dst[1] = b;
}

__global__ __launch_bounds__(256) void lp_f16(
    const float* __restrict__ xyz,
    const float* __restrict__ vdirs,
    const unsigned int* __restrict__ patches,
    float* __restrict__ out,
    int N)
{
    __shared__ float sh[1536];

    int tid = threadIdx.x;
    int b0  = blockIdx.x * 256;
    int nPts = N - b0; nPts = nPts > 256 ? 256 : nPts;
    int nflt = nPts * 3;
    int base4 = (b0 * 3) >> 2;

    const vf4* x4 = (const vf4*)xyz;
    const vf4* d4 = (const vf4*)vdirs;
    if (tid * 4 < nflt) {
        vf4 vx = __builtin_nontemporal_load(&x4[base4 + tid]);
        ((vf4*)sh)[tid] = vx;
        vf4 vd = __builtin_nontemporal_load(&d4[base4 + tid]);
        ((vf4*)(sh + 768))[tid] = vd;
    }
    __syncthreads();

    float r = 0.0f, g = 0.0f, b = 0.0f;
    if (tid < nPts) {
        float x  = sh[3 * tid + 0];
        float y  = sh[3 * tid + 1];
        float z  = sh[3 * tid + 2];
        float dx = sh[768 + 3 * tid + 0];
        float dy = sh[768 + 3 * tid + 1];
        float dz = sh[768 + 3 * tid + 2];

        // ---- 10-candidate separable top-4 selection ----
        float ex0, ex1, ex2, ey0, ey1, ey2, ez0, ez1, ez2;
        int jx0, jx1, jx2, jy0, jy1, jy2, jz0, jz1, jz2;
        dimsort(x, ex0, ex1, ex2, jx0, jx1, jx2);
        dimsort(y, ey0, ey1, ey2, jy0, jy1, jy2);
        dimsort(z, ez0, ez1, ez2, jz0, jz1, jz2);

        int X0 = jx0 * 25, X1 = jx1 * 25, X2 = jx2 * 25;
        int Y0 = jy0 * 5,  Y1 = jy1 * 5,  Y2 = jy2 * 5;
        int Z0 = jz0,      Z1 = jz1,      Z2 = jz2;

        float exy00 = ex0 + ey0, exy10 = ex1 + ey0, exy01 = ex0 + ey1;
        float exy11 = ex1 + ey1, exy20 = ex2 + ey0, exy02 = ex0 + ey2;
        int   kxy00 = X0 + Y0,   kxy10 = X1 + Y0,   kxy01 = X0 + Y1;
        int   kxy11 = X1 + Y1,   kxy20 = X2 + Y0,   kxy02 = X0 + Y2;

        // (0,0,0) is the guaranteed minimum
        float s0 = exy00 + ez0, s1 = 1e30f, s2 = 1e30f, s3 = 1e30f;
        int   k0 = kxy00 + Z0,  k1 = 0,     k2 = 0,     k3 = 0;

        { float d = exy10 + ez0; int L = kxy10 + Z0; INSERT(d, L, s0, s1, s2, s3, k0, k1, k2, k3); }  // 100
        { float d = exy01 + ez0; int L = kxy01 + Z0; INSERT(d, L, s0, s1, s2, s3, k0, k1, k2, k3); }  // 010
        { float d = exy00 + ez1; int L = kxy00 + Z1; INSERT(d, L, s0, s1, s2, s3, k0, k1, k2, k3); }  // 001
        { float d = exy11 + ez0; int L = kxy11 + Z0; INSERT(d, L, s0, s1, s2, s3, k0, k1, k2, k3); }  // 110
        { float d = exy10 + ez1; int L = kxy10 + Z1; INSERT(d, L, s0, s1, s2, s3, k0, k1, k2, k3); }  // 101
        { float d = exy01 + ez1; int L = kxy01 + Z1; INSERT(d, L, s0, s1, s2, s3, k0, k1, k2, k3); }  // 011
        { float d = exy20 + ez0; int L = kxy20 + Z0; INSERT(d, L, s0, s1, s2, s3, k0, k1, k2, k3); }  // 200
        { float d = exy02 + ez0; int L = kxy02 + Z0; INSERT(d, L, s0, s1, s2, s3, k0, k1, k2, k3); }  // 020
        { float d = exy00 + ez2; int L = kxy00 + Z2; INSERT(d, L, s0, s1, s2, s3, k0, k1, k2, k3); }  // 002

        float w0 = fastrcp(fastsqrt(s0) + 1e-4f);
        float w1 = fastrcp(fastsqrt(s1) + 1e-4f);
        float w2 = fastrcp(fastsqrt(s2) + 1e-4f);
        float w3 = fastrcp(fastsqrt(s3) + 1e-4f);
        float wi = fastrcp(w0 + w1 + w2 + w3);
        w0 *= wi; w1 *= wi; w2 *= wi; w3 *= wi;

        int face, t00;
        float w00, w01, w10, w11;
        uv_setup(dx, dy, dz, face, t00, w00, w01, w10, w11);

        int cell = (face * 256 + t00) * 125;
#pragma unroll
        for (int k = 0; k < 4; k++) {
            int   p  = (k == 0) ? k0 : (k == 1) ? k1 : (k == 2) ? k2 : k3;
            float wn = (k == 0) ? w0 : (k == 1) ? w1 : (k == 2) ? w2 : w3;
            const unsigned* pp = patches + (size_t)(cell + p) * 8;
            u32x4 lo = *(const u32x4*)pp;
            u32x2 hi = *(const u32x2*)(pp + 4);
            float r00, g00, b00, r01, g01, b01, r10, g10, b10, r11, g11, b11;
            up2(lo.x, r00, g00);
            up2(lo.y, b00, r01);
            up2(lo.z, g01, b01);
            up2(lo.w, r10, g10);
            up2(hi.x, b10, r11);
            up2(hi.y, g11, b11);
            float rr = fmaf(r00, w00, fmaf(r01, w01, fmaf(r10, w10, r11 * w11)));
            float gg = fmaf(g00, w00, fmaf(g01, w01, fmaf(g10, w10, g11 * w11)));
            float bv = fmaf(b00, w00, fmaf(b01, w01, fmaf(b10, w10, b11 * w11)));
            r = fmaf(wn, rr, r);
            g = fmaf(wn, gg, g);
            b = fmaf(wn, bv, b);
        }
    }

    __syncthreads();
    if (tid < nPts) {
        sh[3 * tid + 0] = r;
        sh[3 * tid + 1] = g;
        sh[3 * tid + 2] = b;
    }
    __syncthreads();
    if (tid * 4 < nflt) {
        vf4* o4 = (vf4*)out;
        __builtin_nontemporal_store(((vf4*)sh)[tid], &o4[base4 + tid]);
    }
}

extern "C" void kernel_launch(void* const* d_in, const int* in_sizes, int n_in,
                              void* d_out, int out_size, void* d_ws, size_t ws_size,
                              hipStream_t stream) {
    const float* xyz  = (const float*)d_in[0];
    const float* vd   = (const float*)d_in[1];
    const float* cube = (const float*)d_in[2];
    float* outp = (float*)d_out;
    int N = in_sizes[0] / 3;
    int blocks = (N + 255) / 256;

    unsigned int* patches = (unsigned int*)d_ws;
    hipLaunchKernelGGL(build_patches_f16, dim3((NPATCH + 255) / 256), dim3(256), 0, stream,
                       cube, patches);
    hipLaunchKernelGGL(lp_f16, dim3(blocks), dim3(256), 0, stream,
                       xyz, vd, patches, outp, N);
}